// Round 10
// baseline (124.141 us; speedup 1.0000x reference)
//
#include <hip/hip_runtime.h>

// ActiveParticles forward pass, N=4096, float32.
// K1: N^2 interaction pass. 256 blocks x 512 thr; block owns 16 i's, each
//     thread tests one staged j against TWO i's. Dense records by particle
//     id (R18): recQuad[i] + recC[i], no atomics, no memset dispatch.
// K2: single-workgroup collision loop, 1024 thr, moved-bitmap skip (R19).
// R20 measured: do-while runs I=9 iterations (WRITE_SIZE canary 32->68KB);
//     K2 = 40us => ~4us/iter mostly FIXED (R18 vs R19: full-gather vs skip
//     differ by only 0.63us/iter => per-slot work is ~15% of iteration).
// R21 (this round): ONE barrier per iteration (was 2) via double-buffered
//     pos[2][]. Read phase reads pos[cur], write phase writes pos[nxt] =>
//     no read/write hazard inside a region; single barrier orders
//     write(k) -> read(k+1).
//     - carry-forward: slot writes pos[nxt] iff moved now OR moved last
//       iter (pm) => both buffers hold latest position (init writes both).
//     - bmp/flg go 3-phase (mod 3): cleared region k, set k+1, probed k+2,
//       each pair barrier-separated => race-free with 1 barrier.
//     - break check moves to loop TOP (reads flg3[it%3] = movers of it-1).
//       Same 9 regions execute; dbg canary must again show WRITE=68KB.
//     Exactness: reads at iter k see exactly end-of-(k-1) positions, same
//     arithmetic, same skip rule => bit-identical.
#define NPART 4096
#define PI_F 3.1415927410125732f
#define TWO_PI_F 6.2831854820251465f
#define SENT 4096              // sentinel neighbor id in padded quads

__device__ __forceinline__ float wrapf(float d) {
    // replicates: d = where(d <= -PI, mod(d, PI), d); d -= (d >= PI)*2PI
    if (d <= -PI_F) {
        d = fmodf(d, PI_F);
        if (d < 0.0f) d += PI_F;     // python-mod sign fixup
    }
    if (d >= PI_F) d -= TWO_PI_F;
    return d;
}

// ---------------- K1: interaction pass + dense record build ----------------
__global__ __launch_bounds__(512)
void k_interact(const float* __restrict__ pr, const float* __restrict__ pim,
                const float* __restrict__ orr, const float* __restrict__ oim,
                const float* __restrict__ deltas,
                const float* __restrict__ rot_noise,
                const float* __restrict__ tn_re, const float* __restrict__ tn_im,
                float* __restrict__ out,
                uint2* __restrict__ recQuad, int* __restrict__ recC,
                unsigned short* __restrict__ recNbr16) {
    constexpr float RR_F  = 8e-6f;
    constexpr float RR2   = RR_F * RR_F;
    constexpr float ROC_F = (float)(2.5e-5 + 3.15e-6);   // RO + RC (max radius)
    constexpr float ROC2  = ROC_F * ROC_F;
    constexpr float CUT_F = 14.3e-6f;                    // 2Rc + 8um candidate cutoff
    constexpr float CUT2  = CUT_F * CUT_F;

    __shared__ float2 lsP[512];                          // staged j positions
    __shared__ float2 lsO[512];                          // staged j orientations
    __shared__ float rA0[512], rA1[512], rA2[512], rA3[512], rA4[512];
    __shared__ float rB0[512], rB1[512], rB2[512], rB3[512], rB4[512];
    __shared__ float cr_[512], ci_[512];
    __shared__ int ncnt[16];
    __shared__ unsigned short nbrL[16 * 16];

    int tid = threadIdx.x;
    int li = tid & 7, sl = tid >> 3;                     // sl in 0..63
    int i0 = blockIdx.x * 16 + li;                       // first owned i
    int i1 = i0 + 8;                                     // second owned i

    if (tid < 16) ncnt[tid] = 0;

    float pxA = pr[i0], pyA = pim[i0], oxA = orr[i0], oyA = oim[i0];
    float pxB = pr[i1], pyB = pim[i1], oxB = orr[i1], oyB = oim[i1];

    float nAr = 0.0f, SAre = 0.0f, SAim = 0.0f, oAre = 0.0f, oAim = 0.0f;
    float nBr = 0.0f, SBre = 0.0f, SBim = 0.0f, oBre = 0.0f, oBim = 0.0f;
    float cs_re = 0.0f, cs_im = 0.0f;

    for (int c = 0; c < 8; ++c) {
        int j0 = c * 512;
        __syncthreads();
        float jr = pr[j0 + tid], ji = pim[j0 + tid];
        lsP[tid] = make_float2(jr, ji);
        lsO[tid] = make_float2(orr[j0 + tid], oim[j0 + tid]);
        cs_re += jr; cs_im += ji;                        // each j staged exactly once
        __syncthreads();
#pragma unroll
        for (int t = 0; t < 8; ++t) {
            int jj = sl * 8 + ((t + sl) & 7);            // bank-swizzled: conflict-free
            int j = j0 + jj;
            float2 pv = lsP[jj];
            float drA = pxA - pv.x, diA = pyA - pv.y;
            float d2A = drA * drA + diA * diA;
            float drB = pxB - pv.x, diB = pyB - pv.y;
            float d2B = drB * drB + diB * diB;
            // ROC is the largest radius: exact superset test for both i's.
            if (__any((d2A <= ROC2) | (d2B <= ROC2))) {  // rare slow path
                float2 ov = lsO[jj];
                // ---- i0 ----
                if (d2A <= ROC2) { oAre += ov.x; oAim += ov.y; }
                float dotA = oxA * ov.x + oyA * ov.y;    // in-front: cos(ai-aj)>0
                if ((d2A <= RR2) & (dotA > 0.0f) & (j != i0)) {
                    nAr += 1.0f; SAre += pv.x; SAim += pv.y;
                }
                if (d2A <= CUT2 && j != i0) {
                    int slot = atomicAdd(&ncnt[li], 1);
                    if (slot < 16) nbrL[li * 16 + slot] = (unsigned short)j;
                }
                // ---- i1 ----
                if (d2B <= ROC2) { oBre += ov.x; oBim += ov.y; }
                float dotB = oxB * ov.x + oyB * ov.y;
                if ((d2B <= RR2) & (dotB > 0.0f) & (j != i1)) {
                    nBr += 1.0f; SBre += pv.x; SBim += pv.y;
                }
                if (d2B <= CUT2 && j != i1) {
                    int slot = atomicAdd(&ncnt[li + 8], 1);
                    if (slot < 16) nbrL[(li + 8) * 16 + slot] = (unsigned short)j;
                }
            }
        }
    }

    rA0[tid] = nAr; rA1[tid] = SAre; rA2[tid] = SAim; rA3[tid] = oAre; rA4[tid] = oAim;
    rB0[tid] = nBr; rB1[tid] = SBre; rB2[tid] = SBim; rB3[tid] = oBre; rB4[tid] = oBim;
    cr_[tid] = cs_re; ci_[tid] = cs_im;
    __syncthreads();
    for (int s = 256; s >= 8; s >>= 1) {                 // tree (li groups, stride>=8)
        if (tid < s) {
            rA0[tid] += rA0[tid + s]; rA1[tid] += rA1[tid + s];
            rA2[tid] += rA2[tid + s]; rA3[tid] += rA3[tid + s];
            rA4[tid] += rA4[tid + s];
            rB0[tid] += rB0[tid + s]; rB1[tid] += rB1[tid + s];
            rB2[tid] += rB2[tid + s]; rB3[tid] += rB3[tid + s];
            rB4[tid] += rB4[tid + s];
            cr_[tid] += cr_[tid + s];  ci_[tid] += ci_[tid + s];
        }
        __syncthreads();
    }
    if (tid < 4) { cr_[tid] += cr_[tid + 4]; ci_[tid] += ci_[tid + 4]; }
    __syncthreads();
    if (tid < 2) { cr_[tid] += cr_[tid + 2]; ci_[tid] += ci_[tid + 2]; }
    __syncthreads();
    if (tid == 0) { cr_[0] += cr_[1]; ci_[0] += ci_[1]; }
    __syncthreads();

    if (tid < 16) {   // per-particle epilogue; i = blk*16 + tid
        int i = blockIdx.x * 16 + tid;
        float n_r, S_re, S_im, o_re, o_im, px, py, ox, oy;
        if (tid < 8) {
            n_r = rA0[tid]; S_re = rA1[tid]; S_im = rA2[tid];
            o_re = rA3[tid]; o_im = rA4[tid];
            px = pxA; py = pyA; ox = oxA; oy = oyA;      // this thread's li == tid
        } else {
            int g = tid - 8;
            n_r = rB0[g]; S_re = rB1[g]; S_im = rB2[g];
            o_re = rB3[g]; o_im = rB4[g];
            px = pxB; py = pyB; ox = oxB; oy = oyB;      // li == tid-8 -> i1 == i
        }

        float maxnr = fmaxf(n_r, 1.0f);
        float sgn = (n_r > 0.0f) ? 1.0f : 0.0f;
        float Sre = S_re / maxnr - px * sgn;
        float Sim = S_im / maxnr - py * sgn;
        float d_re = -Sre, d_im = -Sim;

        float cmsx = cr_[0] * (1.0f / 4096.0f);
        float cmsy = ci_[0] * (1.0f / 4096.0f);
        float Ps_re = cmsx - px;                         // n_a = 4096 > 0
        float Ps_im = cmsy - py;

        float dl = deltas[i];
        float cd = cosf(dl), sd = sinf(dl);
        float l_re = Ps_re * cd - Ps_im * sd;            // Ps * e^{+i d}
        float l_im = Ps_re * sd + Ps_im * cd;
        float r_re = Ps_re * cd + Ps_im * sd;            // Ps * e^{-i d}
        float r_im = Ps_im * cd - Ps_re * sd;

        float nb   = fmaxf(hypotf(o_re, o_im), 1e-14f);
        float na_l = fmaxf(hypotf(l_re, l_im), 1e-14f);
        float na_r = fmaxf(hypotf(r_re, r_im), 1e-14f);
        float csl = (l_re * o_re + l_im * o_im) / (na_l * nb);
        float csr = (r_re * o_re + r_im * o_im) / (na_r * nb);
        float b_re = (csl >= csr) ? l_re : r_re;
        float b_im = (csl >= csr) ? l_im : r_im;

        float ai = atan2f(oy, ox);
        bool has_rep = (d_re != 0.0f) || (d_im != 0.0f);
        float att;
        if (has_rep) att = wrapf(atan2f(d_im, d_re) - ai);
        else         att = wrapf(atan2f(b_im, b_re) - ai);

        constexpr float GDD  = (float)(0.2 * 25.0 * 0.0028);  // DT*GAMMA*DR
        constexpr float S2DR = 0.07483314773547883f;           // sqrt(2*DR)
        constexpr float SDT  = 0.44721359549995793f;           // sqrt(DT)
        float theta = GDD * sinf(att) + (rot_noise[i] * S2DR) * SDT;
        float rr_ = cosf(theta), ri_ = sinf(theta);

        float no_re = ox * rr_ - oy * ri_;
        float no_im = ox * ri_ + oy * rr_;

        constexpr float DTVEL = (float)(0.2 * 5e-7);
        constexpr float C1 = 0.70710678118654752f;             // sqrt(0.5)
        constexpr float C2 = 1.6733200530681511e-07f;          // sqrt(2*DT_TRANS)
        float t_re = DTVEL * ox + ((tn_re[i] * C1) * C2) * SDT;
        float t_im = DTVEL * oy + ((tn_im[i] * C1) * C2) * SDT;
        float p0x = px + t_re, p0y = py + t_im;

        float2* o2 = (float2*)out;
        o2[i]            = make_float2(p0x, p0y);        // K2 reads + may overwrite
        o2[1 * 4096 + i] = make_float2(no_re, no_im);
        o2[2 * 4096 + i] = make_float2(o_re, o_im);
        o2[3 * 4096 + i] = make_float2(l_re, l_im);
        o2[4 * 4096 + i] = make_float2(r_re, r_im);

        // dense record build: unconditional, no atomics, no gcnt.
        int c = min(ncnt[tid], 16);
        unsigned q0 = (c > 0) ? nbrL[tid * 16 + 0] : (unsigned)SENT;
        unsigned q1 = (c > 1) ? nbrL[tid * 16 + 1] : (unsigned)SENT;
        unsigned q2 = (c > 2) ? nbrL[tid * 16 + 2] : (unsigned)SENT;
        unsigned q3 = (c > 3) ? nbrL[tid * 16 + 3] : (unsigned)SENT;
        recQuad[i] = make_uint2(q0 | (q1 << 16), q2 | (q3 << 16));
        recC[i] = c;
        if (c > 4) {                                     // rare tail (~2%)
            int cp = (c + 3) & ~3;
            for (int m = 4; m < cp; ++m)
                recNbr16[i * 16 + m] = (m < c) ? nbrL[tid * 16 + m]
                                               : (unsigned short)SENT;
        }
    }
}

// ---------------- K2: collision loop, ONE workgroup (1024 thr), dense ------
__global__ __launch_bounds__(1024)
void k_coll_all(const uint2* __restrict__ recQuad, const int* __restrict__ recC,
                const unsigned short* __restrict__ recNbr16,
                float* __restrict__ out, int* __restrict__ dbg) {
    constexpr float TWO_RC  = (float)(2.0 * 3.15e-6);
    constexpr float TWO_RC2 = TWO_RC * TWO_RC;
    constexpr float C21RC   = (float)(2.1 * 3.15e-6);

    __shared__ float2 pos[2][NPART + 2];               // R21: double buffer
    __shared__ __align__(16) unsigned short pool[128 * 16];  // c>4 tails
    __shared__ int poolCnt;
    __shared__ unsigned bmp3[3][132];                  // 3-phase moved bitmaps
    __shared__ int flg3[3];                            // 3-phase any-mover flags

    int tid = threadIdx.x;
    if (tid == 0) {
        pos[0][SENT] = make_float2(1e9f, 1e9f);        // sentinels, both buffers
        pos[1][SENT] = make_float2(1e9f, 1e9f);
        poolCnt = 0;
        flg3[0] = 0; flg3[1] = 0; flg3[2] = 0;
    }
    if (tid < 132) {
        bmp3[0][tid] = 0u; bmp3[1][tid] = 0u; bmp3[2][tid] = 0u;
    }

    const float2* o2in = (const float2*)out;           // p0 written by K1
    float myx[4], myy[4];
    int myc[4], myo[4];
    int nq0[4], nq1[4], nq2[4], nq3[4];
    bool pm[4];                                        // self-moved-last-iter
#pragma unroll
    for (int s = 0; s < 4; ++s) {                      // dense, coalesced init
        int i = s * 1024 + tid;
        float2 p = o2in[i];
        myx[s] = p.x; myy[s] = p.y;
        pos[0][i] = p; pos[1][i] = p;                  // both buffers hold p0
        uint2 q = recQuad[i];
        nq0[s] = q.x & 0xffff; nq1[s] = q.x >> 16;
        nq2[s] = q.y & 0xffff; nq3[s] = q.y >> 16;
        myc[s] = recC[i];
        myo[s] = -1;
        pm[s] = false;                                 // init wrote both buffers
    }
    __syncthreads();                                   // pos[][] + poolCnt ready

#pragma unroll
    for (int s = 0; s < 4; ++s) {                      // stage rare tails to LDS
        if (myc[s] > 4) {
            int r = atomicAdd(&poolCnt, 1);
            if (r < 128) {
                int i = s * 1024 + tid;
                const uint4* src = (const uint4*)&recNbr16[i * 16];
                uint4* dst = (uint4*)&pool[r * 16];
                dst[0] = src[0]; dst[1] = src[1];
                myo[s] = r;
            }                                          // overflow: global fallback
        }
    }
    __syncthreads();                                   // pool ready

    // Region schedule (ONE barrier per iteration, at region end):
    //   region it: read pos[it&1], probe bmp3[it%3] (movers of it-1),
    //              clear bmp3/flg3 slot (it+2)%3 (untouched this region),
    //              write pos[(it+1)&1] (moved now OR moved last iter),
    //              movers set bmp3[(it+1)%3] + flg3[(it+1)%3].
    //   break at TOP of region it if flg3[it%3]==0 (no movers at it-1).
    for (int it = 0; it < 30; ++it) {
        if (it > 0 && flg3[it % 3] == 0) break;        // converged at it-1
        int cb = it & 1, nb = cb ^ 1;
        int probeS = it % 3, setS = (it + 1) % 3, clrS = (it + 2) % 3;
        if (tid < 132) bmp3[clrS][tid] = 0u;           // safe: nobody reads/sets clrS
        if (tid == 0) flg3[clrS] = 0;

        dbg[(it << 10) + tid] = it;                    // iter-count canary (WRITE_SIZE)

        float nx[4], ny[4];
        int ncs[4];
#pragma unroll
        for (int s = 0; s < 4; ++s) {                    // read/compute phase
            ncs[s] = 0;
            int c = myc[s];
            if (c > 0) {
                bool dirty;
                if (it == 0 || c > 4) {
                    dirty = true;
                } else {
                    unsigned hit = pm[s] ? 1u : 0u;
                    hit |= (bmp3[probeS][nq0[s] >> 5] >> (nq0[s] & 31)) & 1u;
                    hit |= (bmp3[probeS][nq1[s] >> 5] >> (nq1[s] & 31)) & 1u;
                    hit |= (bmp3[probeS][nq2[s] >> 5] >> (nq2[s] & 31)) & 1u;
                    hit |= (bmp3[probeS][nq3[s] >> 5] >> (nq3[s] & 31)) & 1u;
                    dirty = hit != 0u;
                }
                if (dirty) {
                    float px = myx[s], py = myy[s];
                    float mre = 0.0f, mim = 0.0f;
                    int nc = 0;
                    float2 q0 = pos[cb][nq0[s]], q1 = pos[cb][nq1[s]];
                    float2 q2 = pos[cb][nq2[s]], q3 = pos[cb][nq3[s]];
#define COLL_ONE(q)                                                     \
                    {                                                   \
                        float dr = (q).x - px, di = (q).y - py;         \
                        float d2 = dr * dr + di * di;                   \
                        if (d2 <= TWO_RC2) {                            \
                            float a = sqrtf(d2);                        \
                            float mm = (C21RC - a) * 0.5f / a;          \
                            mre += dr * mm; mim += di * mm; ++nc;       \
                        }                                               \
                    }
                    COLL_ONE(q0) COLL_ONE(q1) COLL_ONE(q2) COLL_ONE(q3)
                    for (int m0 = 4; m0 < c; m0 += 4) {  // rare: c>4 tail
                        uint2 w;
                        if (myo[s] >= 0)
                            w = *(const uint2*)&pool[myo[s] * 16 + m0];
                        else
                            w = *(const uint2*)&recNbr16[(s * 1024 + tid) * 16 + m0];
                        int j0 = w.x & 0xffff, j1 = w.x >> 16;
                        int j2 = w.y & 0xffff, j3 = w.y >> 16;
                        float2 t0 = pos[cb][j0], t1 = pos[cb][j1];
                        float2 t2 = pos[cb][j2], t3 = pos[cb][j3];
                        COLL_ONE(t0) COLL_ONE(t1) COLL_ONE(t2) COLL_ONE(t3)
                    }
#undef COLL_ONE
                    ncs[s] = nc;
                    nx[s] = px - mre; ny[s] = py - mim;
                }
            }
        }
        // write phase: targets pos[nb] / bmp3[setS] / flg3[setS] — none of
        // which any thread reads in this region => no barrier needed here.
        int any = 0;
#pragma unroll
        for (int s = 0; s < 4; ++s) {
            bool moved = (ncs[s] > 0);
            if (moved) { myx[s] = nx[s]; myy[s] = ny[s]; }
            if (moved || pm[s]) {                        // carry-forward rule
                int i = s * 1024 + tid;
                pos[nb][i] = make_float2(myx[s], myy[s]);
            }
            if (moved) {
                int i = s * 1024 + tid;
                atomicOr(&bmp3[setS][i >> 5], 1u << (i & 31));
            }
            pm[s] = moved;
            any |= ncs[s];
        }
        if (any) flg3[setS] = 1;                         // benign race: all write 1
        __syncthreads();                                 // the ONE barrier
    }

    float2* o2 = (float2*)out;                           // final positions, all i
#pragma unroll
    for (int s = 0; s < 4; ++s)
        o2[s * 1024 + tid] = make_float2(myx[s], myy[s]);
}

extern "C" void kernel_launch(void* const* d_in, const int* in_sizes, int n_in,
                              void* d_out, int out_size, void* d_ws, size_t ws_size,
                              hipStream_t stream) {
    const float* pos_re = (const float*)d_in[0];
    const float* pos_im = (const float*)d_in[1];
    const float* ori_re = (const float*)d_in[2];
    const float* ori_im = (const float*)d_in[3];
    const float* deltas = (const float*)d_in[4];
    const float* rot_noise = (const float*)d_in[5];
    const float* tn_re = (const float*)d_in[6];
    const float* tn_im = (const float*)d_in[7];
    float* out = (float*)d_out;

    // dense workspace layout (no counters, no memset dispatch)
    uint2* recQuad = (uint2*)d_ws;                          // 4096 (32 KB)
    int* recC = (int*)(recQuad + NPART);                    // 4096 (16 KB)
    unsigned short* recNbr16 = (unsigned short*)(recC + NPART);  // 4096*16 (128 KB)
    int* dbg = (int*)(recNbr16 + NPART * 16);               // 30*4 KB iter channel

    k_interact<<<256, 512, 0, stream>>>(pos_re, pos_im, ori_re, ori_im,
                                        deltas, rot_noise, tn_re, tn_im,
                                        out, recQuad, recC, recNbr16);
    k_coll_all<<<1, 1024, 0, stream>>>(recQuad, recC, recNbr16, out, dbg);
}